// Round 22
// baseline (69.896 us; speedup 1.0000x reference)
//
#include <hip/hip_runtime.h>
#include <hip/hip_bf16.h>

// EdgeLearnGNN: B=16, N=64, F=1024, K=13, C=2
// Round 21: r21 (race-fixed, 64.0us) + r20's XCD producer->consumer alignment.
// r20's failure is now attributed: the uninitialized ticket counter (fixed in
// r21 by k1 zeroing bar) -- the permutation only changed arrival timing and
// exposed it. The alignment mechanism is real: without it, k2's gpart-tile
// reads are produced on a DIFFERENT XCD (cross-die L3 latency); with it they
// are 100% same-XCD L2 hits, spart[b] 50% local, k3 aligned to k2's h2 writes.
// Pure block-index permutation: identical values, different placement.
//   K1: 768 blocks: 512 GEMM g=x@W^T (64x64 x K512, XCD-local) | 256 spart+warm
//       (block 0 zeroes the k3 ticket counter -> race-free terminal ticket)
//   K2: 256 blocks x 512 thr (b,ft): adj recompute + h2=(A+I)@g+gin_b + BN1 part
//   K3: 64 blocks: BN1 reduce + folded mix + conv13 + BN2 part + [ticket-63: head]

typedef __attribute__((ext_vector_type(8))) __bf16 bf16x8;
typedef __attribute__((ext_vector_type(4))) float f32x4;

__device__ __forceinline__ unsigned short f2bf(float f) {
  union { float f; unsigned int u; } v; v.f = f;
  unsigned int r = v.u + 0x7FFFu + ((v.u >> 16) & 1u);   // RNE, finite values only
  return (unsigned short)(r >> 16);
}

// ---------------- K1: XCD-local GEMM (bid<512) + spart tiles (bid>=512) ----------------
__global__ __launch_bounds__(256) void k1_spart_gemm(
    const float* __restrict__ x, const float* __restrict__ w,
    const float* __restrict__ gin_W,
    float* __restrict__ spart, float* __restrict__ gpart,
    unsigned* __restrict__ bar) {
  __shared__ __align__(16) union {
    struct { float xt[64 * 68]; float wt[64]; } s;
    struct { unsigned short A[64 * 72]; unsigned short B[64 * 72]; } g;   // 18.4 KB
  } sm;
  int t = threadIdx.x, bid = blockIdx.x;

  // RACE FIX (r21): zero the k3 ticket counter every launch; visible to k3 via
  // kernel-boundary coherence. Tickets 0..63 -> residue 63 = true last arriver.
  if (bid == 0 && t == 0) *bar = 0u;

  if (bid >= 512) {
    // ----- pairwise weighted-L1 partial scores + gin_W warm, XCD-aligned map -----
    // sbid&7 = xcd; b = 4*(xcd&3)+(rem&3); ft = ((xcd>>2)<<3)|(rem>>2).
    // Batch b's 16 tiles live on XCDs {b>>2, 4+(b>>2)} (ft-halves) -> k2 co-locates.
    int sbid = bid - 512;
    int sxcd = sbid & 7, srem = sbid >> 3;
    int b = 4 * (sxcd & 3) + (srem & 3);
    int ft = ((sxcd >> 2) << 3) | (srem >> 2);
    int f0 = ft * 64;
    int widx = b * 16 + ft;                    // spart storage index (layout unchanged)
    const float4* pf = reinterpret_cast<const float4*>(gin_W) + (size_t)widx * 1024 + t;
    float4 pf0 = pf[0], pf1 = pf[256], pf2 = pf[512], pf3 = pf[768];
    for (int c = 0; c < 16; ++c) {
      int idx = c * 256 + t;
      int n = idx >> 6, f = idx & 63;
      sm.s.xt[n * 68 + f] = x[b * 65536 + n * 1024 + f0 + f];
    }
    if (t < 64) sm.s.wt[t] = w[f0 + t];
    __syncthreads();
    asm volatile("" :: "v"(pf0.x), "v"(pf1.x), "v"(pf2.x), "v"(pf3.x));  // keep loads live
    int i0 = (t >> 4) * 4, j0 = (t & 15) * 4;
    float acc[4][4];
#pragma unroll
    for (int ii = 0; ii < 4; ++ii)
#pragma unroll
      for (int jj = 0; jj < 4; ++jj) acc[ii][jj] = 0.f;
    for (int f = 0; f < 64; f += 4) {
      float4 wv = *reinterpret_cast<const float4*>(&sm.s.wt[f]);
      float4 av[4], bv[4];
#pragma unroll
      for (int ii = 0; ii < 4; ++ii) av[ii] = *reinterpret_cast<const float4*>(&sm.s.xt[(i0 + ii) * 68 + f]);
#pragma unroll
      for (int jj = 0; jj < 4; ++jj) bv[jj] = *reinterpret_cast<const float4*>(&sm.s.xt[(j0 + jj) * 68 + f]);
#pragma unroll
      for (int ii = 0; ii < 4; ++ii)
#pragma unroll
        for (int jj = 0; jj < 4; ++jj) {
          acc[ii][jj] += fabsf(av[ii].x - bv[jj].x) * wv.x
                       + fabsf(av[ii].y - bv[jj].y) * wv.y
                       + fabsf(av[ii].z - bv[jj].z) * wv.z
                       + fabsf(av[ii].w - bv[jj].w) * wv.w;
        }
    }
    float* out = spart + (size_t)widx * 4096;
#pragma unroll
    for (int ii = 0; ii < 4; ++ii)
#pragma unroll
      for (int jj = 0; jj < 4; ++jj)
        out[(i0 + ii) * 64 + (j0 + jj)] = acc[ii][jj];
    return;
  }

  // ----- GEMM g = x @ W^T: 512 blocks, tile 64x64, K-slice 512, XCD regions -----
  int g = bid;
  int xcd = g & 7, idx = g >> 3;
  int lt = idx & 31, slice = idx >> 5;
  int tr = 4 * (xcd & 3) + (lt >> 3);      // 0..15 (M-tile of 64 rows)
  int tc = 8 * (xcd >> 2) + (lt & 7);      // 0..15 (N-tile of 64 cols)
  int k0 = slice * 512;
  int wave = t >> 6, lane = t & 63;
  int wr = wave * 16;                      // wave: 16 rows x 64 cols
  int lrow = lane & 15, kg = lane >> 4;
  f32x4 acc[4];
#pragma unroll
  for (int nj = 0; nj < 4; ++nj) acc[nj] = f32x4{0.f, 0.f, 0.f, 0.f};

  for (int chunk = 0; chunk < 8; ++chunk) {
    int kc = k0 + chunk * 64;
#pragma unroll
    for (int u = 0; u < 4; ++u) {            // A: 64 rows x 64 k
      int idx4 = u * 256 + t;
      int row = idx4 >> 4, kq = idx4 & 15;
      float4 va = *reinterpret_cast<const float4*>(&x[(size_t)(tr * 64 + row) * 1024 + kc + kq * 4]);
      ushort4 ua; ua.x = f2bf(va.x); ua.y = f2bf(va.y); ua.z = f2bf(va.z); ua.w = f2bf(va.w);
      *reinterpret_cast<ushort4*>(&sm.g.A[row * 72 + kq * 4]) = ua;
    }
#pragma unroll
    for (int u = 0; u < 4; ++u) {            // B: 64 rows x 64 k
      int idx4 = u * 256 + t;
      int row = idx4 >> 4, kq = idx4 & 15;
      float4 vb = *reinterpret_cast<const float4*>(&gin_W[(size_t)(tc * 64 + row) * 1024 + kc + kq * 4]);
      ushort4 ub; ub.x = f2bf(vb.x); ub.y = f2bf(vb.y); ub.z = f2bf(vb.z); ub.w = f2bf(vb.w);
      *reinterpret_cast<ushort4*>(&sm.g.B[row * 72 + kq * 4]) = ub;
    }
    __syncthreads();
#pragma unroll
    for (int ks = 0; ks < 2; ++ks) {
      bf16x8 a = *reinterpret_cast<const bf16x8*>(&sm.g.A[(wr + lrow) * 72 + ks * 32 + kg * 8]);
      bf16x8 bf_[4];
#pragma unroll
      for (int nj = 0; nj < 4; ++nj)
        bf_[nj] = *reinterpret_cast<const bf16x8*>(&sm.g.B[(nj * 16 + lrow) * 72 + ks * 32 + kg * 8]);
#pragma unroll
      for (int nj = 0; nj < 4; ++nj)
        acc[nj] = __builtin_amdgcn_mfma_f32_16x16x32_bf16(a, bf_[nj], acc[nj], 0, 0, 0);
    }
    __syncthreads();
  }
  float* gp = gpart + (size_t)slice * (1024u * 1024u);
#pragma unroll
  for (int nj = 0; nj < 4; ++nj) {
    int row = tr * 64 + wr + kg * 4;              // C/D: row = (lane>>4)*4 + reg
    int col = tc * 64 + nj * 16 + lrow;           // col = lane&15
#pragma unroll
    for (int r = 0; r < 4; ++r)
      gp[(size_t)(row + r) * 1024 + col] = acc[nj][r];
  }
}

// ---- K2: 512 threads. adj[b] recompute + h2 = (A+I)@g + gin_b + BN1 partials. ----
// XCD-aligned: block (b,ft) on xcd = ((ft>>3)<<2)|(b>>2) -> its gpart tile is
// produced on the SAME XCD (L2-local); spart[b] half-local. Thread owns: gt 2
// rows; adj 2x4 patch; h2 2 rows x 4 cols.
__global__ __launch_bounds__(512) void k2_adj_h2(
    const float* __restrict__ spart, const float* __restrict__ gpart,
    const float* __restrict__ gin_b,
    float* __restrict__ dout, float* __restrict__ h2, float* __restrict__ part) {
  __shared__ float adjs[64 * 65];
  __shared__ float csum[32][64];
  __shared__ float cinv[64];
  __shared__ __align__(16) float gt[64 * 68];
  int t = threadIdx.x, bid = blockIdx.x;
  int xcd = bid & 7, rem = bid >> 3;          // rem 0..31
  int b = 4 * (xcd & 3) + (rem & 3);
  int ft = ((xcd >> 2) << 3) | (rem >> 2);
  int f0 = ft * 64;
  // g tile: sum the 2 K-slice partials -> gt[64][68] (thread: 2 rows)
  {
    int i = t >> 4, fl = (t & 15) * 4;          // i in 0..31
#pragma unroll
    for (int c = 0; c < 2; ++c) {
      int row = c * 32 + i;
      const float* base = gpart + (size_t)(b * 64 + row) * 1024 + f0 + fl;
      float4 s0 = *reinterpret_cast<const float4*>(base);
      float4 s1 = *reinterpret_cast<const float4*>(base + (1u << 20));
      float4 g4;
      g4.x = s0.x + s1.x; g4.y = s0.y + s1.y;
      g4.z = s0.z + s1.z; g4.w = s0.w + s1.w;
      *reinterpret_cast<float4*>(&gt[row * 68 + fl]) = g4;
    }
  }
  // adj[b] from spart: thread owns rows tr2*2..+1 x cols tj*4..+3
  int tj = t & 15, tr2 = t >> 4;              // tr2 in 0..31
  float4 v4[2];
#pragma unroll
  for (int r = 0; r < 2; ++r) v4[r] = make_float4(0.f, 0.f, 0.f, 0.f);
  for (int ft2 = 0; ft2 < 16; ++ft2) {
    const float* p = spart + (size_t)(b * 16 + ft2) * 4096 + tj * 4;
#pragma unroll
    for (int r = 0; r < 2; ++r) {
      float4 s = *reinterpret_cast<const float4*>(&p[(tr2 * 2 + r) * 64]);
      v4[r].x += s.x; v4[r].y += s.y; v4[r].z += s.z; v4[r].w += s.w;
    }
  }
  float4 colsum = make_float4(0.f, 0.f, 0.f, 0.f);
#pragma unroll
  for (int r = 0; r < 2; ++r) {
    float4 e;
    e.x = expf(-fmaxf(v4[r].x, 0.f));
    e.y = expf(-fmaxf(v4[r].y, 0.f));
    e.z = expf(-fmaxf(v4[r].z, 0.f));
    e.w = expf(-fmaxf(v4[r].w, 0.f));
    int row = tr2 * 2 + r;
    adjs[row * 65 + tj * 4 + 0] = e.x;
    adjs[row * 65 + tj * 4 + 1] = e.y;
    adjs[row * 65 + tj * 4 + 2] = e.z;
    adjs[row * 65 + tj * 4 + 3] = e.w;
    colsum.x += e.x; colsum.y += e.y; colsum.z += e.z; colsum.w += e.w;
  }
  csum[tr2][tj * 4 + 0] = colsum.x;
  csum[tr2][tj * 4 + 1] = colsum.y;
  csum[tr2][tj * 4 + 2] = colsum.z;
  csum[tr2][tj * 4 + 3] = colsum.w;
  __syncthreads();
  if (t < 64) {
    float s = 0.f;
#pragma unroll
    for (int g2 = 0; g2 < 32; ++g2) s += csum[g2][t];
    cinv[t] = 1.f / s;
  }
  __syncthreads();
  float* doutAdj = dout + 32 + (size_t)b * 4096;
#pragma unroll
  for (int r = 0; r < 2; ++r) {
    int row = tr2 * 2 + r;
#pragma unroll
    for (int c = 0; c < 4; ++c) {
      int col = tj * 4 + c;
      float a = adjs[row * 65 + col] * cinv[col];
      adjs[row * 65 + col] = a;
      if (ft == 0) doutAdj[row * 64 + col] = a;
    }
  }
  __syncthreads();
  // h2 tile = gt (identity) + adj@gt + gin_b; 2 rows x 4 cols per thread
  int i0 = (t >> 4) * 2, fl = (t & 15) * 4;   // i0: 0..62 step 2
  float4 gbv = *reinterpret_cast<const float4*>(&gin_b[f0 + fl]);
  float4 acc4[2];
  acc4[0] = *reinterpret_cast<const float4*>(&gt[i0 * 68 + fl]);        // identity
  acc4[1] = *reinterpret_cast<const float4*>(&gt[(i0 + 1) * 68 + fl]);
  for (int j = 0; j < 64; ++j) {
    float4 gv = *reinterpret_cast<const float4*>(&gt[j * 68 + fl]);
    float a0 = adjs[i0 * 65 + j], a1 = adjs[(i0 + 1) * 65 + j];
    acc4[0].x += a0 * gv.x; acc4[0].y += a0 * gv.y; acc4[0].z += a0 * gv.z; acc4[0].w += a0 * gv.w;
    acc4[1].x += a1 * gv.x; acc4[1].y += a1 * gv.y; acc4[1].z += a1 * gv.z; acc4[1].w += a1 * gv.w;
  }
  float rs[2], rq[2];
#pragma unroll
  for (int ii = 0; ii < 2; ++ii) {
    acc4[ii].x += gbv.x; acc4[ii].y += gbv.y; acc4[ii].z += gbv.z; acc4[ii].w += gbv.w;
    *reinterpret_cast<float4*>(&h2[(size_t)(b * 64 + i0 + ii) * 1024 + f0 + fl]) = acc4[ii];
    rs[ii] = (acc4[ii].x + acc4[ii].y) + (acc4[ii].z + acc4[ii].w);
    rq[ii] = (acc4[ii].x * acc4[ii].x + acc4[ii].y * acc4[ii].y)
           + (acc4[ii].z * acc4[ii].z + acc4[ii].w * acc4[ii].w);
  }
#pragma unroll
  for (int m = 1; m < 16; m <<= 1) {
#pragma unroll
    for (int r = 0; r < 2; ++r) {
      rs[r] += __shfl_xor(rs[r], m, 64);
      rq[r] += __shfl_xor(rq[r], m, 64);
    }
  }
  if ((t & 15) == 0) {
    float* pp = part + (size_t)(b * 16 + ft) * 128;
#pragma unroll
    for (int r = 0; r < 2; ++r) {
      int n = i0 + r;
      pp[2 * n]     = rs[r];
      pp[2 * n + 1] = rq[r];
    }
  }
}

// ---- K3: 64 blocks (b, 256-f quarter), XCD-aligned to k2's h2 writes:
//      xcd = ((fq>>1)<<2)|(b>>2). BN1 reduce + folded mix + conv13 + BN2 partials;
//      ticket 63 (true last arriver, bar zeroed by k1) runs the head inline. ----
__global__ __launch_bounds__(256) void k3_y_head(
    const float* __restrict__ h2, const float* __restrict__ part,
    const float* __restrict__ lc_W, const float* __restrict__ lc_b,
    const float* __restrict__ bn1_g, const float* __restrict__ bn1_b,
    const float* __restrict__ conv_W, const float* __restrict__ conv_b,
    const float* __restrict__ bn2_g, const float* __restrict__ bn2_b,
    const float* __restrict__ out_W, const float* __restrict__ out_b,
    float* __restrict__ y2, float* __restrict__ bn2part,
    float* __restrict__ dout, unsigned* __restrict__ bar) {
  __shared__ float redp[2][128];
  __shared__ float cls[64], dds[64];
  __shared__ float yloc[268];
  __shared__ float red[256], red2[256];
  __shared__ float c0s;
  __shared__ unsigned tk;
  int t = threadIdx.x, bid = blockIdx.x;
  int xcd = bid & 7, rem = bid >> 3;          // rem 0..7
  int b = 4 * (xcd & 3) + (rem & 3);
  int fq = ((xcd >> 2) << 1) | (rem >> 2);
  int f0 = fq * 256;
  {
    int k = t & 127, h = t >> 7;
    float s = 0.f;
    const float* pp = part + (size_t)h * 128 * 128 + k;
    for (int p = 0; p < 128; ++p) s += pp[(size_t)p * 128];
    redp[h][k] = s;
  }
  __syncthreads();
  if (t < 64) {
    float sum = redp[0][2 * t] + redp[1][2 * t];
    float sq  = redp[0][2 * t + 1] + redp[1][2 * t + 1];
    float m = sum * (1.f / 16384.f);
    float var = sq * (1.f / 16384.f) - m * m;     // biased, as jnp.var
    float inv = 1.f / sqrtf(var + 1e-5f);
    float g = bn1_g[t], be = bn1_b[t], lw = lc_W[t];
    cls[t] = lw * g * inv;
    dds[t] = lw * (be - m * inv * g);
  }
  __syncthreads();
  if (t == 0) {
    float s = 0.f;
    for (int n = 0; n < 64; ++n) s += dds[n];
    c0s = s + lc_b[0];
  }
  __syncthreads();
  float c0 = c0s;
  for (int idx = t; idx < 268; idx += 256) {
    int f = f0 - 6 + idx;
    float acc = 0.f;
    if (f >= 0 && f < 1024) {
      acc = c0;
      const float* col = h2 + (size_t)(b * 64) * 1024 + f;
      for (int n = 0; n < 64; ++n) acc += cls[n] * col[(size_t)n * 1024];
    }
    yloc[idx] = acc;
  }
  __syncthreads();
  float cw[13];
#pragma unroll
  for (int k = 0; k < 13; ++k) cw[k] = conv_W[k];
  float vv = conv_b[0];
#pragma unroll
  for (int k = 0; k < 13; ++k) vv += yloc[t + k] * cw[k];
  y2[b * 1024 + f0 + t] = vv;
  red[t] = vv; red2[t] = vv * vv;
  __syncthreads();
  for (int off = 128; off > 0; off >>= 1) {
    if (t < off) { red[t] += red[t + off]; red2[t] += red2[t + off]; }
    __syncthreads();
  }
  if (t == 0) {
    int dchunk = b * 4 + fq;
    bn2part[2 * dchunk] = red[0]; bn2part[2 * dchunk + 1] = red2[0];
  }

  // --- terminal ticket: bar zeroed by k1 each launch -> tickets 0..63; ticket 63
  //     is the TRUE last arriver (all 63 others release-fenced). Zero waiting. ---
  __syncthreads();                                 // all block stores drained (vmcnt)
  if (t == 0) { __threadfence(); tk = atomicAdd(bar, 1u); }
  __syncthreads();
  if (tk != 63u) return;
  __threadfence();                                 // acquire: see all blocks' y2/bn2part

  {
    float S = 0.f, S2 = 0.f;
    for (int i = 0; i < 64; ++i) { S += bn2part[2 * i]; S2 += bn2part[2 * i + 1]; }
    float m2 = S * (1.f / 16384.f);
    float inv2 = 1.f / sqrtf(S2 * (1.f / 16384.f) - m2 * m2 + 1e-5f);
    float g2 = bn2_g[0] * inv2, be2 = bn2_b[0];
    int hb = t >> 4, seg = t & 15;
    const float4* yv = reinterpret_cast<const float4*>(&y2[hb * 1024 + seg * 64]);
    const float4* w0 = reinterpret_cast<const float4*>(&out_W[seg * 64]);
    const float4* w1 = reinterpret_cast<const float4*>(&out_W[1024 + seg * 64]);
    float a0 = 0.f, a1 = 0.f;
#pragma unroll 4
    for (int u = 0; u < 16; ++u) {
      float4 y4 = yv[u], cc0 = w0[u], cc1 = w1[u];
      float vx = fmaxf((y4.x - m2) * g2 + be2, 0.f);
      float vy = fmaxf((y4.y - m2) * g2 + be2, 0.f);
      float vz = fmaxf((y4.z - m2) * g2 + be2, 0.f);
      float vw = fmaxf((y4.w - m2) * g2 + be2, 0.f);
      a0 += vx * cc0.x + vy * cc0.y + vz * cc0.z + vw * cc0.w;
      a1 += vx * cc1.x + vy * cc1.y + vz * cc1.z + vw * cc1.w;
    }
    red[t] = a0; red2[t] = a1;                     // reuse reduction arrays
    __syncthreads();
    for (int off = 8; off > 0; off >>= 1) {
      if (seg < off) { red[t] += red[t + off]; red2[t] += red2[t + off]; }
      __syncthreads();
    }
    if (seg == 0) {
      float l0 = red[t] + out_b[0], l1 = red2[t] + out_b[1];
      float mx = fmaxf(l0, l1);
      float e0 = expf(l0 - mx), e1 = expf(l1 - mx);
      float inv = 1.f / (e0 + e1);
      dout[hb * 2 + 0] = e0 * inv;
      dout[hb * 2 + 1] = e1 * inv;
    }
  }
}

extern "C" void kernel_launch(void* const* d_in, const int* in_sizes, int n_in,
                              void* d_out, int out_size, void* d_ws, size_t ws_size,
                              hipStream_t stream) {
  (void)in_sizes; (void)n_in; (void)out_size; (void)ws_size;
  const float* x      = (const float*)d_in[0];
  const float* w      = (const float*)d_in[1];
  const float* gin_W  = (const float*)d_in[2];
  const float* gin_b  = (const float*)d_in[3];
  const float* bn1_g  = (const float*)d_in[4];
  const float* bn1_b  = (const float*)d_in[5];
  const float* lc_W   = (const float*)d_in[6];
  const float* lc_b   = (const float*)d_in[7];
  const float* conv_W = (const float*)d_in[8];
  const float* conv_b = (const float*)d_in[9];
  const float* bn2_g  = (const float*)d_in[10];
  const float* bn2_b  = (const float*)d_in[11];
  const float* out_W  = (const float*)d_in[12];
  const float* out_b  = (const float*)d_in[13];
  float* dout = (float*)d_out;

  char* ws = (char*)d_ws;
  float* spart   = (float*)ws;                                  // 4 MB
  float* h2      = (float*)(ws + (4u << 20));                   // 4 MB
  float* gpart   = (float*)(ws + (8u << 20));                   // 8 MB (2 K-slices)
  float* part    = (float*)(ws + (16u << 20));                  // 128 KB (256 x 128 f32)
  float* y2      = (float*)(ws + (16u << 20) + (128u << 10));   // 64 KB
  float* bn2part = (float*)(ws + (16u << 20) + (192u << 10));   // 128 f32
  unsigned* bar  = (unsigned*)(ws + (16u << 20) + (194u << 10)); // ticket counter (k1 zeroes)

  k1_spart_gemm<<<dim3(768), dim3(256), 0, stream>>>(x, w, gin_W, spart, gpart, bar);
  k2_adj_h2    <<<dim3(256), dim3(512), 0, stream>>>(spart, gpart, gin_b, dout, h2, part);
  k3_y_head    <<<dim3(64),  dim3(256), 0, stream>>>(h2, part, lc_W, lc_b, bn1_g, bn1_b,
                                                     conv_W, conv_b, bn2_g, bn2_b, out_W, out_b,
                                                     y2, bn2part, dout, bar);
}

// Round 23
// 57.607 us; speedup vs baseline: 1.2133x; 1.2133x over previous
//
#include <hip/hip_runtime.h>
#include <hip/hip_bf16.h>

// EdgeLearnGNN: B=16, N=64, F=1024, K=13, C=2
// Round 22: r22's profile finally exposed k3_y_head = 43us (FETCH 2.8MB @ 67GB/s,
// occupancy 1.6%) -- the dominant kernel all session, previously hidden under the
// harness fills. Fixes (k1/k2 XCD maps reverted to r21; r22's remap was -5.9us):
//  1. BN1 stats reduce hoisted into K2's terminal ticket (2nd counter): last
//     k2 arriver reduces part (128KB) once -> stats[128]. Removes 64x128KB
//     redundant reads from k3.
//  2. K3: 64 -> 256 blocks (b, 64-f slice), 4-way channel-split y-phase
//     (thread q=t>>6 sums 16 channels) -> 16x more memory parallelism on the
//     stride-4KB h2 reads that were fetch-latency-bound at 67 GB/s.
//  3. bn2part 256 partials; k3 terminal ticket 255; head reduces via LDS tree.
//   K1: 768 blocks: 512 GEMM (64x64 x K512, XCD-local) | 256 spart+warm (+bar zero)
//   K2: 256 blocks x 512 thr: adj + h2 + BN1 part + [ticket-255: stats reduce]
//   K3: 256 blocks: folded mix + conv13 + BN2 part + [ticket-255: head]

typedef __attribute__((ext_vector_type(8))) __bf16 bf16x8;
typedef __attribute__((ext_vector_type(4))) float f32x4;

__device__ __forceinline__ unsigned short f2bf(float f) {
  union { float f; unsigned int u; } v; v.f = f;
  unsigned int r = v.u + 0x7FFFu + ((v.u >> 16) & 1u);   // RNE, finite values only
  return (unsigned short)(r >> 16);
}

// ---------------- K1: XCD-local GEMM (bid<512) + spart tiles (bid>=512) ----------------
__global__ __launch_bounds__(256) void k1_spart_gemm(
    const float* __restrict__ x, const float* __restrict__ w,
    const float* __restrict__ gin_W,
    float* __restrict__ spart, float* __restrict__ gpart,
    unsigned* __restrict__ bar) {
  __shared__ __align__(16) union {
    struct { float xt[64 * 68]; float wt[64]; } s;
    struct { unsigned short A[64 * 72]; unsigned short B[64 * 72]; } g;   // 18.4 KB
  } sm;
  int t = threadIdx.x, bid = blockIdx.x;

  // RACE FIX: zero BOTH ticket counters every launch (k2 stats @bar[16], k3 head
  // @bar[0]); visible downstream via kernel-boundary coherence.
  if (bid == 0 && t == 0) { bar[0] = 0u; bar[16] = 0u; }

  if (bid >= 512) {
    // ----- pairwise weighted-L1 partial scores, tile (b, ft) + gin_W warm -----
    int sbid = bid - 512;
    int b = sbid >> 4, ft = sbid & 15, f0 = ft * 64;
    const float4* pf = reinterpret_cast<const float4*>(gin_W) + (size_t)sbid * 1024 + t;
    float4 pf0 = pf[0], pf1 = pf[256], pf2 = pf[512], pf3 = pf[768];
    for (int c = 0; c < 16; ++c) {
      int idx = c * 256 + t;
      int n = idx >> 6, f = idx & 63;
      sm.s.xt[n * 68 + f] = x[b * 65536 + n * 1024 + f0 + f];
    }
    if (t < 64) sm.s.wt[t] = w[f0 + t];
    __syncthreads();
    asm volatile("" :: "v"(pf0.x), "v"(pf1.x), "v"(pf2.x), "v"(pf3.x));  // keep loads live
    int i0 = (t >> 4) * 4, j0 = (t & 15) * 4;
    float acc[4][4];
#pragma unroll
    for (int ii = 0; ii < 4; ++ii)
#pragma unroll
      for (int jj = 0; jj < 4; ++jj) acc[ii][jj] = 0.f;
    for (int f = 0; f < 64; f += 4) {
      float4 wv = *reinterpret_cast<const float4*>(&sm.s.wt[f]);
      float4 av[4], bv[4];
#pragma unroll
      for (int ii = 0; ii < 4; ++ii) av[ii] = *reinterpret_cast<const float4*>(&sm.s.xt[(i0 + ii) * 68 + f]);
#pragma unroll
      for (int jj = 0; jj < 4; ++jj) bv[jj] = *reinterpret_cast<const float4*>(&sm.s.xt[(j0 + jj) * 68 + f]);
#pragma unroll
      for (int ii = 0; ii < 4; ++ii)
#pragma unroll
        for (int jj = 0; jj < 4; ++jj) {
          acc[ii][jj] += fabsf(av[ii].x - bv[jj].x) * wv.x
                       + fabsf(av[ii].y - bv[jj].y) * wv.y
                       + fabsf(av[ii].z - bv[jj].z) * wv.z
                       + fabsf(av[ii].w - bv[jj].w) * wv.w;
        }
    }
    float* out = spart + (size_t)sbid * 4096;
#pragma unroll
    for (int ii = 0; ii < 4; ++ii)
#pragma unroll
      for (int jj = 0; jj < 4; ++jj)
        out[(i0 + ii) * 64 + (j0 + jj)] = acc[ii][jj];
    return;
  }

  // ----- GEMM g = x @ W^T: 512 blocks, tile 64x64, K-slice 512, XCD regions -----
  int g = bid;
  int xcd = g & 7, idx = g >> 3;
  int lt = idx & 31, slice = idx >> 5;
  int tr = 4 * (xcd & 3) + (lt >> 3);      // 0..15 (M-tile of 64 rows)
  int tc = 8 * (xcd >> 2) + (lt & 7);      // 0..15 (N-tile of 64 cols)
  int k0 = slice * 512;
  int wave = t >> 6, lane = t & 63;
  int wr = wave * 16;                      // wave: 16 rows x 64 cols
  int lrow = lane & 15, kg = lane >> 4;
  f32x4 acc[4];
#pragma unroll
  for (int nj = 0; nj < 4; ++nj) acc[nj] = f32x4{0.f, 0.f, 0.f, 0.f};

  for (int chunk = 0; chunk < 8; ++chunk) {
    int kc = k0 + chunk * 64;
#pragma unroll
    for (int u = 0; u < 4; ++u) {            // A: 64 rows x 64 k
      int idx4 = u * 256 + t;
      int row = idx4 >> 4, kq = idx4 & 15;
      float4 va = *reinterpret_cast<const float4*>(&x[(size_t)(tr * 64 + row) * 1024 + kc + kq * 4]);
      ushort4 ua; ua.x = f2bf(va.x); ua.y = f2bf(va.y); ua.z = f2bf(va.z); ua.w = f2bf(va.w);
      *reinterpret_cast<ushort4*>(&sm.g.A[row * 72 + kq * 4]) = ua;
    }
#pragma unroll
    for (int u = 0; u < 4; ++u) {            // B: 64 rows x 64 k
      int idx4 = u * 256 + t;
      int row = idx4 >> 4, kq = idx4 & 15;
      float4 vb = *reinterpret_cast<const float4*>(&gin_W[(size_t)(tc * 64 + row) * 1024 + kc + kq * 4]);
      ushort4 ub; ub.x = f2bf(vb.x); ub.y = f2bf(vb.y); ub.z = f2bf(vb.z); ub.w = f2bf(vb.w);
      *reinterpret_cast<ushort4*>(&sm.g.B[row * 72 + kq * 4]) = ub;
    }
    __syncthreads();
#pragma unroll
    for (int ks = 0; ks < 2; ++ks) {
      bf16x8 a = *reinterpret_cast<const bf16x8*>(&sm.g.A[(wr + lrow) * 72 + ks * 32 + kg * 8]);
      bf16x8 bf_[4];
#pragma unroll
      for (int nj = 0; nj < 4; ++nj)
        bf_[nj] = *reinterpret_cast<const bf16x8*>(&sm.g.B[(nj * 16 + lrow) * 72 + ks * 32 + kg * 8]);
#pragma unroll
      for (int nj = 0; nj < 4; ++nj)
        acc[nj] = __builtin_amdgcn_mfma_f32_16x16x32_bf16(a, bf_[nj], acc[nj], 0, 0, 0);
    }
    __syncthreads();
  }
  float* gp = gpart + (size_t)slice * (1024u * 1024u);
#pragma unroll
  for (int nj = 0; nj < 4; ++nj) {
    int row = tr * 64 + wr + kg * 4;              // C/D: row = (lane>>4)*4 + reg
    int col = tc * 64 + nj * 16 + lrow;           // col = lane&15
#pragma unroll
    for (int r = 0; r < 4; ++r)
      gp[(size_t)(row + r) * 1024 + col] = acc[nj][r];
  }
}

// ---- K2: 512 threads. adj[b] recompute + h2 = (A+I)@g + gin_b + BN1 partials;
//      terminal ticket 255 -> last arriver reduces part -> stats[128] (m, inv). ----
__global__ __launch_bounds__(512) void k2_adj_h2(
    const float* __restrict__ spart, const float* __restrict__ gpart,
    const float* __restrict__ gin_b,
    float* __restrict__ dout, float* __restrict__ h2, float* __restrict__ part,
    float* __restrict__ stats, unsigned* __restrict__ bar) {
  __shared__ float adjs[64 * 65];
  __shared__ float csum[32][64];
  __shared__ float cinv[64];
  __shared__ __align__(16) float gt[64 * 68];
  __shared__ float redps[4][128];
  __shared__ unsigned tk;
  int t = threadIdx.x, bid = blockIdx.x;
  int xcd = bid & 7, local = bid >> 3;
  int b = (xcd << 1) | (local & 1);
  int ft = local >> 1;
  int f0 = ft * 64;
  // g tile: sum the 2 K-slice partials -> gt[64][68] (thread: 2 rows)
  {
    int i = t >> 4, fl = (t & 15) * 4;          // i in 0..31
#pragma unroll
    for (int c = 0; c < 2; ++c) {
      int row = c * 32 + i;
      const float* base = gpart + (size_t)(b * 64 + row) * 1024 + f0 + fl;
      float4 s0 = *reinterpret_cast<const float4*>(base);
      float4 s1 = *reinterpret_cast<const float4*>(base + (1u << 20));
      float4 g4;
      g4.x = s0.x + s1.x; g4.y = s0.y + s1.y;
      g4.z = s0.z + s1.z; g4.w = s0.w + s1.w;
      *reinterpret_cast<float4*>(&gt[row * 68 + fl]) = g4;
    }
  }
  // adj[b] from spart: thread owns rows tr2*2..+1 x cols tj*4..+3
  int tj = t & 15, tr2 = t >> 4;              // tr2 in 0..31
  float4 v4[2];
#pragma unroll
  for (int r = 0; r < 2; ++r) v4[r] = make_float4(0.f, 0.f, 0.f, 0.f);
  for (int ft2 = 0; ft2 < 16; ++ft2) {
    const float* p = spart + (size_t)(b * 16 + ft2) * 4096 + tj * 4;
#pragma unroll
    for (int r = 0; r < 2; ++r) {
      float4 s = *reinterpret_cast<const float4*>(&p[(tr2 * 2 + r) * 64]);
      v4[r].x += s.x; v4[r].y += s.y; v4[r].z += s.z; v4[r].w += s.w;
    }
  }
  float4 colsum = make_float4(0.f, 0.f, 0.f, 0.f);
#pragma unroll
  for (int r = 0; r < 2; ++r) {
    float4 e;
    e.x = expf(-fmaxf(v4[r].x, 0.f));
    e.y = expf(-fmaxf(v4[r].y, 0.f));
    e.z = expf(-fmaxf(v4[r].z, 0.f));
    e.w = expf(-fmaxf(v4[r].w, 0.f));
    int row = tr2 * 2 + r;
    adjs[row * 65 + tj * 4 + 0] = e.x;
    adjs[row * 65 + tj * 4 + 1] = e.y;
    adjs[row * 65 + tj * 4 + 2] = e.z;
    adjs[row * 65 + tj * 4 + 3] = e.w;
    colsum.x += e.x; colsum.y += e.y; colsum.z += e.z; colsum.w += e.w;
  }
  csum[tr2][tj * 4 + 0] = colsum.x;
  csum[tr2][tj * 4 + 1] = colsum.y;
  csum[tr2][tj * 4 + 2] = colsum.z;
  csum[tr2][tj * 4 + 3] = colsum.w;
  __syncthreads();
  if (t < 64) {
    float s = 0.f;
#pragma unroll
    for (int g2 = 0; g2 < 32; ++g2) s += csum[g2][t];
    cinv[t] = 1.f / s;
  }
  __syncthreads();
  float* doutAdj = dout + 32 + (size_t)b * 4096;
#pragma unroll
  for (int r = 0; r < 2; ++r) {
    int row = tr2 * 2 + r;
#pragma unroll
    for (int c = 0; c < 4; ++c) {
      int col = tj * 4 + c;
      float a = adjs[row * 65 + col] * cinv[col];
      adjs[row * 65 + col] = a;
      if (ft == 0) doutAdj[row * 64 + col] = a;
    }
  }
  __syncthreads();
  // h2 tile = gt (identity) + adj@gt + gin_b; 2 rows x 4 cols per thread
  int i0 = (t >> 4) * 2, fl = (t & 15) * 4;   // i0: 0..62 step 2
  float4 gbv = *reinterpret_cast<const float4*>(&gin_b[f0 + fl]);
  float4 acc4[2];
  acc4[0] = *reinterpret_cast<const float4*>(&gt[i0 * 68 + fl]);        // identity
  acc4[1] = *reinterpret_cast<const float4*>(&gt[(i0 + 1) * 68 + fl]);
  for (int j = 0; j < 64; ++j) {
    float4 gv = *reinterpret_cast<const float4*>(&gt[j * 68 + fl]);
    float a0 = adjs[i0 * 65 + j], a1 = adjs[(i0 + 1) * 65 + j];
    acc4[0].x += a0 * gv.x; acc4[0].y += a0 * gv.y; acc4[0].z += a0 * gv.z; acc4[0].w += a0 * gv.w;
    acc4[1].x += a1 * gv.x; acc4[1].y += a1 * gv.y; acc4[1].z += a1 * gv.z; acc4[1].w += a1 * gv.w;
  }
  float rs[2], rq[2];
#pragma unroll
  for (int ii = 0; ii < 2; ++ii) {
    acc4[ii].x += gbv.x; acc4[ii].y += gbv.y; acc4[ii].z += gbv.z; acc4[ii].w += gbv.w;
    *reinterpret_cast<float4*>(&h2[(size_t)(b * 64 + i0 + ii) * 1024 + f0 + fl]) = acc4[ii];
    rs[ii] = (acc4[ii].x + acc4[ii].y) + (acc4[ii].z + acc4[ii].w);
    rq[ii] = (acc4[ii].x * acc4[ii].x + acc4[ii].y * acc4[ii].y)
           + (acc4[ii].z * acc4[ii].z + acc4[ii].w * acc4[ii].w);
  }
#pragma unroll
  for (int m = 1; m < 16; m <<= 1) {
#pragma unroll
    for (int r = 0; r < 2; ++r) {
      rs[r] += __shfl_xor(rs[r], m, 64);
      rq[r] += __shfl_xor(rq[r], m, 64);
    }
  }
  if ((t & 15) == 0) {
    float* pp = part + (size_t)(b * 16 + ft) * 128;
#pragma unroll
    for (int r = 0; r < 2; ++r) {
      int n = i0 + r;
      pp[2 * n]     = rs[r];
      pp[2 * n + 1] = rq[r];
    }
  }

  // --- terminal ticket (bar[16], zeroed by k1): last arriver reduces part->stats ---
  __syncthreads();                                 // all block stores drained
  if (t == 0) { __threadfence(); tk = atomicAdd(&bar[16], 1u); }
  __syncthreads();
  if (tk != 255u) return;
  __threadfence();                                 // acquire: all part entries visible
  {
    int slot = t & 127, quarter = t >> 7;          // 4 quarters x 64 tiles
    float s = 0.f;
    const float* pp = part + (size_t)quarter * 64 * 128 + slot;
    for (int p = 0; p < 64; ++p) s += pp[(size_t)p * 128];
    redps[quarter][slot] = s;
    __syncthreads();
    if (t < 64) {
      float sum = (redps[0][2 * t] + redps[1][2 * t]) + (redps[2][2 * t] + redps[3][2 * t]);
      float sq  = (redps[0][2 * t + 1] + redps[1][2 * t + 1]) + (redps[2][2 * t + 1] + redps[3][2 * t + 1]);
      float m = sum * (1.f / 16384.f);
      float var = sq * (1.f / 16384.f) - m * m;    // biased, as jnp.var
      stats[2 * t]     = m;
      stats[2 * t + 1] = 1.f / sqrtf(var + 1e-5f);
    }
  }
}

// ---- K3: 256 blocks (b, 64-f slice). Folded BN1+lc mix (4-way channel split) +
//      conv13 + BN2 partials; terminal ticket 255 runs the head inline. ----
__global__ __launch_bounds__(256) void k3_y_head(
    const float* __restrict__ h2, const float* __restrict__ stats,
    const float* __restrict__ lc_W, const float* __restrict__ lc_b,
    const float* __restrict__ bn1_g, const float* __restrict__ bn1_b,
    const float* __restrict__ conv_W, const float* __restrict__ conv_b,
    const float* __restrict__ bn2_g, const float* __restrict__ bn2_b,
    const float* __restrict__ out_W, const float* __restrict__ out_b,
    float* __restrict__ y2, float* __restrict__ bn2part,
    float* __restrict__ dout, unsigned* __restrict__ bar) {
  __shared__ float cls[64], dds[64];
  __shared__ float plds[4][76];
  __shared__ float yloc[76];
  __shared__ float red[256], red2[256];
  __shared__ float c0s;
  __shared__ unsigned tk;
  int t = threadIdx.x, bid = blockIdx.x;
  int b = bid >> 4, fq = bid & 15;
  int f0 = fq * 64;
  if (t < 64) {
    float m = stats[2 * t], inv = stats[2 * t + 1];
    float g = bn1_g[t], be = bn1_b[t], lw = lc_W[t];
    cls[t] = lw * g * inv;
    dds[t] = lw * (be - m * inv * g);
  }
  __syncthreads();
  if (t == 0) {
    float s = 0.f;
    for (int n = 0; n < 64; ++n) s += dds[n];
    c0s = s + lc_b[0];
  }
  __syncthreads();
  // y partials: thread (q = t>>6, il = t&63) sums channels q*16..+15 for idx=il(,+64)
  {
    int q = t >> 6, il = t & 63;
    for (int idx = il; idx < 76; idx += 64) {
      int f = f0 - 6 + idx;
      float acc = 0.f;
      if (f >= 0 && f < 1024) {
        const float* col = h2 + (size_t)(b * 64) * 1024 + f;
#pragma unroll
        for (int n = 0; n < 16; ++n) acc += cls[q * 16 + n] * col[(size_t)(q * 16 + n) * 1024];
      }
      plds[q][idx] = acc;
    }
  }
  __syncthreads();
  if (t < 76) {
    int f = f0 - 6 + t;
    float v = 0.f;
    if (f >= 0 && f < 1024)
      v = c0s + ((plds[0][t] + plds[1][t]) + (plds[2][t] + plds[3][t]));
    yloc[t] = v;
  }
  __syncthreads();
  if (t < 64) {
    float cw[13];
#pragma unroll
    for (int k = 0; k < 13; ++k) cw[k] = conv_W[k];
    float vv = conv_b[0];
#pragma unroll
    for (int k = 0; k < 13; ++k) vv += yloc[t + k] * cw[k];
    y2[b * 1024 + f0 + t] = vv;
    // wave-reduce (threads 0..63 = wave 0) the block's BN2 partials
    float s = vv, s2 = vv * vv;
#pragma unroll
    for (int m = 1; m < 64; m <<= 1) {
      s  += __shfl_xor(s, m, 64);
      s2 += __shfl_xor(s2, m, 64);
    }
    if (t == 0) { bn2part[2 * bid] = s; bn2part[2 * bid + 1] = s2; }
  }

  // --- terminal ticket (bar[0], zeroed by k1): ticket 255 = true last arriver ---
  __syncthreads();                                 // all block stores drained
  if (t == 0) { __threadfence(); tk = atomicAdd(&bar[0], 1u); }
  __syncthreads();
  if (tk != 255u) return;
  __threadfence();                                 // acquire: all y2/bn2part visible

  {
    // reduce 256 bn2 partials via LDS tree
    red[t] = bn2part[2 * t]; red2[t] = bn2part[2 * t + 1];
    __syncthreads();
    for (int off = 128; off > 0; off >>= 1) {
      if (t < off) { red[t] += red[t + off]; red2[t] += red2[t + off]; }
      __syncthreads();
    }
    float S = red[0], S2 = red2[0];
    float m2 = S * (1.f / 16384.f);
    float inv2 = 1.f / sqrtf(S2 * (1.f / 16384.f) - m2 * m2 + 1e-5f);
    float g2 = bn2_g[0] * inv2, be2 = bn2_b[0];
    __syncthreads();
    int hb = t >> 4, seg = t & 15;
    const float4* yv = reinterpret_cast<const float4*>(&y2[hb * 1024 + seg * 64]);
    const float4* w0 = reinterpret_cast<const float4*>(&out_W[seg * 64]);
    const float4* w1 = reinterpret_cast<const float4*>(&out_W[1024 + seg * 64]);
    float a0 = 0.f, a1 = 0.f;
#pragma unroll 4
    for (int u = 0; u < 16; ++u) {
      float4 y4 = yv[u], cc0 = w0[u], cc1 = w1[u];
      float vx = fmaxf((y4.x - m2) * g2 + be2, 0.f);
      float vy = fmaxf((y4.y - m2) * g2 + be2, 0.f);
      float vz = fmaxf((y4.z - m2) * g2 + be2, 0.f);
      float vw = fmaxf((y4.w - m2) * g2 + be2, 0.f);
      a0 += vx * cc0.x + vy * cc0.y + vz * cc0.z + vw * cc0.w;
      a1 += vx * cc1.x + vy * cc1.y + vz * cc1.z + vw * cc1.w;
    }
    red[t] = a0; red2[t] = a1;
    __syncthreads();
    for (int off = 8; off > 0; off >>= 1) {
      if (seg < off) { red[t] += red[t + off]; red2[t] += red2[t + off]; }
      __syncthreads();
    }
    if (seg == 0) {
      float l0 = red[t] + out_b[0], l1 = red2[t] + out_b[1];
      float mx = fmaxf(l0, l1);
      float e0 = expf(l0 - mx), e1 = expf(l1 - mx);
      float inv = 1.f / (e0 + e1);
      dout[hb * 2 + 0] = e0 * inv;
      dout[hb * 2 + 1] = e1 * inv;
    }
  }
}

extern "C" void kernel_launch(void* const* d_in, const int* in_sizes, int n_in,
                              void* d_out, int out_size, void* d_ws, size_t ws_size,
                              hipStream_t stream) {
  (void)in_sizes; (void)n_in; (void)out_size; (void)ws_size;
  const float* x      = (const float*)d_in[0];
  const float* w      = (const float*)d_in[1];
  const float* gin_W  = (const float*)d_in[2];
  const float* gin_b  = (const float*)d_in[3];
  const float* bn1_g  = (const float*)d_in[4];
  const float* bn1_b  = (const float*)d_in[5];
  const float* lc_W   = (const float*)d_in[6];
  const float* lc_b   = (const float*)d_in[7];
  const float* conv_W = (const float*)d_in[8];
  const float* conv_b = (const float*)d_in[9];
  const float* bn2_g  = (const float*)d_in[10];
  const float* bn2_b  = (const float*)d_in[11];
  const float* out_W  = (const float*)d_in[12];
  const float* out_b  = (const float*)d_in[13];
  float* dout = (float*)d_out;

  char* ws = (char*)d_ws;
  float* spart   = (float*)ws;                                  // 4 MB
  float* h2      = (float*)(ws + (4u << 20));                   // 4 MB
  float* gpart   = (float*)(ws + (8u << 20));                   // 8 MB (2 K-slices)
  float* part    = (float*)(ws + (16u << 20));                  // 128 KB (256 x 128 f32)
  float* y2      = (float*)(ws + (16u << 20) + (128u << 10));   // 64 KB
  float* bn2part = (float*)(ws + (16u << 20) + (192u << 10));   // 2 KB (256 x 2 f32)
  float* stats   = (float*)(ws + (16u << 20) + (194u << 10));   // 512 B (64 x 2 f32)
  unsigned* bar  = (unsigned*)(ws + (16u << 20) + (195u << 10)); // 2 ticket counters (k1 zeroes)

  k1_spart_gemm<<<dim3(768), dim3(256), 0, stream>>>(x, w, gin_W, spart, gpart, bar);
  k2_adj_h2    <<<dim3(256), dim3(512), 0, stream>>>(spart, gpart, gin_b, dout, h2, part,
                                                     stats, bar);
  k3_y_head    <<<dim3(256), dim3(256), 0, stream>>>(h2, stats, lc_W, lc_b, bn1_g, bn1_b,
                                                     conv_W, conv_b, bn2_g, bn2_b, out_W, out_b,
                                                     y2, bn2part, dout, bar);
}